// Round 1
// baseline (718.586 us; speedup 1.0000x reference)
//
#include <hip/hip_runtime.h>
#include <stdint.h>

typedef short bf16x8 __attribute__((ext_vector_type(8)));
typedef float f32x4  __attribute__((ext_vector_type(4)));

#define NNODES    32768
#define KNB       16
#define FDIM      128
#define KTOT      384      // stacked GEMM K: [neighbors | aspects | nodes]
#define NEG_SLOPE 0.2f

// fp32 -> bf16 round-to-nearest-even (inputs are finite normals; no NaN path)
static __device__ __forceinline__ unsigned short f2bf(float x) {
  union { float f; unsigned u; } v; v.f = x;
  unsigned r = v.u + 0x7fffu + ((v.u >> 16) & 1u);
  return (unsigned short)(r >> 16);
}

static __device__ __forceinline__ bf16x8 pack8(f32x4 lo, f32x4 hi) {
  bf16x8 r;
  r[0] = (short)f2bf(lo[0]); r[1] = (short)f2bf(lo[1]);
  r[2] = (short)f2bf(lo[2]); r[3] = (short)f2bf(lo[3]);
  r[4] = (short)f2bf(hi[0]); r[5] = (short)f2bf(hi[1]);
  r[6] = (short)f2bf(hi[2]); r[7] = (short)f2bf(hi[3]);
  return r;
}

// ---------------------------------------------------------------------------
// Prep: Bmat[o][f], f in [0,384) = [ M1 | M2 | W ] as bf16, where
//   M1 = Wa[:, :128] @ W,  M2 = Wa[:, 128:] @ W   (fused linear_proj+Wa)
// Row-major [o][f] is exactly the B^T layout the MFMA B-fragment wants.
// ---------------------------------------------------------------------------
__global__ void prep_weights(const float* __restrict__ W,
                             const float* __restrict__ Wa,
                             unsigned short* __restrict__ Bmat) {
  const int o = blockIdx.x;    // 0..127
  const int f = threadIdx.x;   // 0..127
  const float* war = Wa + o * 256;
  float a1 = 0.f, a2 = 0.f;
  #pragma unroll 8
  for (int j = 0; j < 128; ++j) {
    float w = W[j * 128 + f];          // coalesced across threads
    a1 = fmaf(war[j], w, a1);
    a2 = fmaf(war[128 + j], w, a2);
  }
  Bmat[o * KTOT + f]       = f2bf(a1);
  Bmat[o * KTOT + 128 + f] = f2bf(a2);
  Bmat[o * KTOT + 256 + f] = f2bf(W[o * 128 + f]);
}

// ---------------------------------------------------------------------------
// Main: per wave, 2 nodes. For each node: D[16x128] = A[16x384] * B[384x128]
// via mfma_f32_16x16x32_bf16 (12 k-steps x 8 col-tiles). A streamed straight
// from global fp32 (rows contiguous), converted to bf16 in-register; B frags
// read from the L2-resident Bmat. No LDS, no barriers.
// Epilogue: t = D + ba; e = exp(lrelu(t)); out = elu(sum_k score*e + bias).
// ---------------------------------------------------------------------------
__global__ void grn_main(const float* __restrict__ nodes,
                         const float* __restrict__ neighbors,
                         const float* __restrict__ aspects,
                         const float* __restrict__ scores,
                         const unsigned short* __restrict__ Bmat,
                         const float* __restrict__ ba,
                         const float* __restrict__ bias,
                         float* __restrict__ out) {
  const int lane = threadIdx.x & 63;
  const int wv   = threadIdx.x >> 6;     // wave in block: 0..3
  const int quad = lane >> 4;            // 0..3
  const int l16  = lane & 15;            // 0..15
  const int n0   = blockIdx.x * 8 + wv * 2;  // 2 nodes per wave

  f32x4 acc[2][8];
  #pragma unroll
  for (int i = 0; i < 2; ++i)
    #pragma unroll
    for (int ct = 0; ct < 8; ++ct)
      acc[i][ct] = (f32x4){0.f, 0.f, 0.f, 0.f};

  // K-loop over stacked 384: kc 0..3 neighbors, 4..7 aspects, 8..11 nodes
  #pragma unroll
  for (int kc = 0; kc < 12; ++kc) {
    const int seg = kc >> 2;
    const int fo  = (kc & 3) * 32 + quad * 8;   // lane's k-offset within segment
    bf16x8 afrag[2];
    #pragma unroll
    for (int i = 0; i < 2; ++i) {
      const int n = n0 + i;
      const float* src;
      if (seg == 0)      src = neighbors + (size_t)(n * KNB + l16) * FDIM + fo;
      else if (seg == 1) src = aspects   + (size_t)(n * KNB + l16) * FDIM + fo;
      else               src = nodes     + (size_t)n * FDIM + fo;  // row-broadcast
      f32x4 lo = *(const f32x4*)src;
      f32x4 hi = *(const f32x4*)(src + 4);
      afrag[i] = pack8(lo, hi);
    }
    // B fragment: lane holds B^T[o = ct*16+l16][k = kc*32+quad*8 + j]
    const unsigned short* bbase = Bmat + (size_t)l16 * KTOT + kc * 32 + quad * 8;
    #pragma unroll
    for (int ct = 0; ct < 8; ++ct) {
      bf16x8 bfrag = *(const bf16x8*)(bbase + (size_t)(ct * 16) * KTOT);
      acc[0][ct] = __builtin_amdgcn_mfma_f32_16x16x32_bf16(afrag[0], bfrag, acc[0][ct], 0, 0, 0);
      acc[1][ct] = __builtin_amdgcn_mfma_f32_16x16x32_bf16(afrag[1], bfrag, acc[1][ct], 0, 0, 0);
    }
  }

  // Epilogue. D layout: lane holds D[row = quad*4 + r][col = ct*16 + l16].
  #pragma unroll
  for (int i = 0; i < 2; ++i) {
    const int n = n0 + i;
    f32x4 sc = *(const f32x4*)(scores + (size_t)n * KNB + quad * 4);
    #pragma unroll
    for (int ct = 0; ct < 8; ++ct) {
      const int c = ct * 16 + l16;
      const float bav = ba[c];
      float s = 0.f;
      #pragma unroll
      for (int r = 0; r < 4; ++r) {
        float t  = acc[i][ct][r] + bav;          // node_proj already in D (broadcast rows)
        float lr = t > 0.f ? t : NEG_SLOPE * t;
        s = fmaf(__expf(lr), sc[r], s);
      }
      // sum over the 16 edge-rows: 4 in-lane (above) x 4 quads (below)
      s += __shfl_xor(s, 16);
      s += __shfl_xor(s, 32);
      if ((ct & 3) == quad) {                    // spread stores across quads
        float v = s + bias[c];
        out[(size_t)n * FDIM + c] = v > 0.f ? v : (__expf(v) - 1.f);
      }
    }
  }
}

extern "C" void kernel_launch(void* const* d_in, const int* in_sizes, int n_in,
                              void* d_out, int out_size, void* d_ws, size_t ws_size,
                              hipStream_t stream) {
  const float* nodes     = (const float*)d_in[0];
  const float* neighbors = (const float*)d_in[1];
  const float* aspects   = (const float*)d_in[2];
  const float* scores    = (const float*)d_in[3];
  const float* W         = (const float*)d_in[4];
  const float* Wa        = (const float*)d_in[5];
  const float* ba        = (const float*)d_in[6];
  const float* bias      = (const float*)d_in[7];
  unsigned short* Bmat   = (unsigned short*)d_ws;   // 128*384*2 = 96 KB

  prep_weights<<<128, 128, 0, stream>>>(W, Wa, Bmat);
  grn_main<<<NNODES / 8, 256, 0, stream>>>(nodes, neighbors, aspects, scores,
                                           Bmat, ba, bias, (float*)d_out);
}

// Round 2
// 677.767 us; speedup vs baseline: 1.0602x; 1.0602x over previous
//
#include <hip/hip_runtime.h>
#include <hip/hip_bf16.h>
#include <stdint.h>

typedef short bf16x8 __attribute__((ext_vector_type(8)));
typedef float f32x4  __attribute__((ext_vector_type(4)));
typedef float f32x2  __attribute__((ext_vector_type(2)));

#define NNODES    32768
#define KNB       16
#define FDIM      128
#define KTOT      384      // stacked GEMM K: [neighbors | aspects | nodes]
#define NEG_SLOPE 0.2f

// fp32 -> bf16 round-to-nearest-even (scalar; used in prep only)
static __device__ __forceinline__ unsigned short f2bf(float x) {
  union { float f; unsigned u; } v; v.f = x;
  unsigned r = v.u + 0x7fffu + ((v.u >> 16) & 1u);
  return (unsigned short)(r >> 16);
}

// packed HW conversion: 8 fp32 -> bf16x8 (4x v_cvt_pk_bf16_f32 path)
static __device__ __forceinline__ bf16x8 pack8(f32x4 lo, f32x4 hi) {
  union { __hip_bfloat162 h[4]; bf16x8 v; } u;
  u.h[0] = __float22bfloat162_rn(make_float2(lo[0], lo[1]));
  u.h[1] = __float22bfloat162_rn(make_float2(lo[2], lo[3]));
  u.h[2] = __float22bfloat162_rn(make_float2(hi[0], hi[1]));
  u.h[3] = __float22bfloat162_rn(make_float2(hi[2], hi[3]));
  return u.v;
}

// ---------------------------------------------------------------------------
// Prep: Bmat[o][f], f in [0,384) = [ M1 | M2 | W ] as bf16, where
//   M1 = Wa[:, :128] @ W,  M2 = Wa[:, 128:] @ W   (fused linear_proj+Wa)
// Row-major [o][f] == B^T layout the MFMA B-fragment wants (verified R1).
// ---------------------------------------------------------------------------
__global__ void prep_weights(const float* __restrict__ W,
                             const float* __restrict__ Wa,
                             unsigned short* __restrict__ Bmat) {
  const int o = blockIdx.x;    // 0..127
  const int f = threadIdx.x;   // 0..127
  const float* war = Wa + o * 256;
  float a1 = 0.f, a2 = 0.f;
  #pragma unroll 8
  for (int j = 0; j < 128; ++j) {
    float w = W[j * 128 + f];          // coalesced across threads
    a1 = fmaf(war[j], w, a1);
    a2 = fmaf(war[128 + j], w, a2);
  }
  Bmat[o * KTOT + f]       = f2bf(a1);
  Bmat[o * KTOT + 128 + f] = f2bf(a2);
  Bmat[o * KTOT + 256 + f] = f2bf(W[o * 128 + f]);
}

// ---------------------------------------------------------------------------
// Main. Per wave: 2 nodes, D[16x128] = A[16x384] * B[384x128].
// Phase 1: ALL A fp32 loaded from global in 12-load batches (deep MLP),
//          converted to 24 bf16x8 fragments held in registers.
// Phase 2: pure compute loop: B frags from L2-resident Bmat + MFMA.
// Epilogue: per-edge exp(lrelu)+score-weighted k-sum (shuffle reduce),
//          LDS transpose so stores are full 512B coalesced lines.
// ---------------------------------------------------------------------------
__global__ void grn_main(const float* __restrict__ nodes,
                         const float* __restrict__ neighbors,
                         const float* __restrict__ aspects,
                         const float* __restrict__ scores,
                         const unsigned short* __restrict__ Bmat,
                         const float* __restrict__ ba,
                         const float* __restrict__ bias,
                         float* __restrict__ out) {
  const int lane = threadIdx.x & 63;
  const int wv   = threadIdx.x >> 6;     // wave in block: 0..3
  const int quad = lane >> 4;            // 0..3
  const int l16  = lane & 15;            // 0..15
  const int n0   = blockIdx.x * 8 + wv * 2;

  __shared__ float xpose[4][2][FDIM];    // 4 KB: store-transpose buffer

  // ---- Phase 1: A preload (2 nodes x 12 kc fragments) ----
  bf16x8 afrag[2][12];
  #pragma unroll
  for (int i = 0; i < 2; ++i) {
    const int n = n0 + i;
    const float* nb = neighbors + ((size_t)n * KNB + l16) * FDIM;
    const float* as = aspects   + ((size_t)n * KNB + l16) * FDIM;
    const float* nd = nodes     + (size_t)n * FDIM;
    #pragma unroll
    for (int h = 0; h < 2; ++h) {        // two 6-kc batches -> 12 loads in flight
      f32x4 lo[6], hi[6];
      #pragma unroll
      for (int j = 0; j < 6; ++j) {
        const int kc  = h * 6 + j;
        const int seg = kc >> 2;
        const int fo  = (kc & 3) * 32 + quad * 8;
        const float* src = (seg == 0) ? nb + fo : (seg == 1) ? as + fo : nd + fo;
        lo[j] = *(const f32x4*)src;
        hi[j] = *(const f32x4*)(src + 4);
      }
      #pragma unroll
      for (int j = 0; j < 6; ++j) afrag[i][h * 6 + j] = pack8(lo[j], hi[j]);
    }
  }

  // ---- Phase 2: compute ----
  f32x4 acc[2][8];
  #pragma unroll
  for (int i = 0; i < 2; ++i)
    #pragma unroll
    for (int ct = 0; ct < 8; ++ct)
      acc[i][ct] = (f32x4){0.f, 0.f, 0.f, 0.f};

  #pragma unroll
  for (int kc = 0; kc < 12; ++kc) {
    const unsigned short* bbase = Bmat + (size_t)l16 * KTOT + kc * 32 + quad * 8;
    #pragma unroll
    for (int ct = 0; ct < 8; ++ct) {
      bf16x8 bfrag = *(const bf16x8*)(bbase + (size_t)(ct * 16) * KTOT);
      acc[0][ct] = __builtin_amdgcn_mfma_f32_16x16x32_bf16(afrag[0][kc], bfrag, acc[0][ct], 0, 0, 0);
      acc[1][ct] = __builtin_amdgcn_mfma_f32_16x16x32_bf16(afrag[1][kc], bfrag, acc[1][ct], 0, 0, 0);
    }
  }

  // ---- Epilogue. D layout: lane holds D[row = quad*4 + r][col = ct*16 + l16].
  #pragma unroll
  for (int i = 0; i < 2; ++i) {
    const int n = n0 + i;
    f32x4 sc = *(const f32x4*)(scores + (size_t)n * KNB + quad * 4);
    #pragma unroll
    for (int ct = 0; ct < 8; ++ct) {
      const int c = ct * 16 + l16;
      const float bav = ba[c];
      float s = 0.f;
      #pragma unroll
      for (int r = 0; r < 4; ++r) {
        float t  = acc[i][ct][r] + bav;          // node_proj already in D (broadcast rows)
        float lr = t > 0.f ? t : NEG_SLOPE * t;
        s = fmaf(__expf(lr), sc[r], s);
      }
      s += __shfl_xor(s, 16);                    // reduce 4 quads (16 edge rows total)
      s += __shfl_xor(s, 32);
      if ((ct & 3) == quad) xpose[wv][i][c] = s; // one quad owns each col-tile
    }
  }
  __syncthreads();

  // full-line stores: lane L writes cols {2L, 2L+1} -> 512 B contiguous per node
  #pragma unroll
  for (int i = 0; i < 2; ++i) {
    f32x2 sv = *(const f32x2*)&xpose[wv][i][2 * lane];
    f32x2 bv = *(const f32x2*)(bias + 2 * lane);
    float v0 = sv[0] + bv[0];
    float v1 = sv[1] + bv[1];
    v0 = v0 > 0.f ? v0 : (__expf(v0) - 1.f);
    v1 = v1 > 0.f ? v1 : (__expf(v1) - 1.f);
    *(f32x2*)(out + (size_t)(n0 + i) * FDIM + 2 * lane) = (f32x2){v0, v1};
  }
}

extern "C" void kernel_launch(void* const* d_in, const int* in_sizes, int n_in,
                              void* d_out, int out_size, void* d_ws, size_t ws_size,
                              hipStream_t stream) {
  const float* nodes     = (const float*)d_in[0];
  const float* neighbors = (const float*)d_in[1];
  const float* aspects   = (const float*)d_in[2];
  const float* scores    = (const float*)d_in[3];
  const float* W         = (const float*)d_in[4];
  const float* Wa        = (const float*)d_in[5];
  const float* ba        = (const float*)d_in[6];
  const float* bias      = (const float*)d_in[7];
  unsigned short* Bmat   = (unsigned short*)d_ws;   // 128*384*2 = 96 KB

  prep_weights<<<128, 128, 0, stream>>>(W, Wa, Bmat);
  grn_main<<<NNODES / 8, 256, 0, stream>>>(nodes, neighbors, aspects, scores,
                                           Bmat, ba, bias, (float*)d_out);
}